// Round 12
// baseline (61.420 us; speedup 1.0000x reference)
//
#include <hip/hip_runtime.h>

// CWT, truncated direct correlation, REAL PART ONLY (harness validates
// out_size = B*128*N float32 = real part of the complex64 reference).
// u-shifted: y[n] = sum_{u=1..T} xpad[n+u]*tw[u], xpad[i]=x[i-8192] (0 outside),
// tw[u] = exp(-(u-1)^2/2sig^2)*cos(2pi*f*(u-1)), sig=6*scale/2pi, f=1/scale,
// T = ceil(5*sigma)+1 <= 307 (validated: absmax 0.0625 vs threshold 0.445).
// ch%4 -> x row, ch%32 -> wavelet; 4|32 -> 32 unique channels, 4 copies.
//
// R9-R11 lesson: FMA count, LDS use, occupancy(2->4.5 w/SIMD), tap-load source
// all ~null -> the coupled wave structure (staging+serial loop+scattered
// 4-copy stores+zero duty in ONE wave) is the suspect. R12 decouples:
//   prep       -> xpad (1MB) + taps (48KB) in ws
//   cwt_unique -> 32 unique channels into ws (8.4MB), 8192 waves, RPT=4
//   bcast      -> pure-BW fill-shaped broadcast 8.4MB -> 33.5MB out
// If this still lands ~29us the floor is environmental; write it up and stop.

#define NPIX   16384
#define NSCALE 32
#define NCH    4
#define ALPHA  5.0f
#define PI_F   3.14159265358979f

#define TSZ    384                    // tap slots per scale (f4-padded)
#define TAPS_F (NSCALE * TSZ)         // 12288 floats
#define XROW   16768                  // padded row [8192 zeros][x row][pad]
#define XPAD_F (16 * XROW)            // 268288 floats
#define YU_F   (TAPS_F + XPAD_F)      // yu offset in ws (floats), 16B-aligned
#define TMAX   307

__global__ __launch_bounds__(256) void prep_kernel(
    const float* __restrict__ x,
    const float* __restrict__ scales,
    float* __restrict__ ws)
{
    const int idx = blockIdx.x * 256 + threadIdx.x;
    if (blockIdx.x < 262) {                 // xpad: 16*16768/4 = 67072 float4
        float4* xp4 = reinterpret_cast<float4*>(ws + TAPS_F);
        const int row = idx / (XROW / 4);
        const int i   = (idx % (XROW / 4)) * 4;
        float4 v = {0.f, 0.f, 0.f, 0.f};
        if (i >= 8192 && i - 8192 < NPIX)   // aligned, no straddle
            v = *reinterpret_cast<const float4*>(x + (size_t)row * NPIX + (i - 8192));
        xp4[idx] = v;
    } else {                                 // taps: 32*384 = 12288 floats
        const int t = idx - 262 * 256;
        if (t < TAPS_F) {
            const int s = t / TSZ, u = t % TSZ;
            const float scale = scales[s];
            const float f     = 1.0f / scale;
            const float sigma = 6.0f * scale / (2.0f * PI_F);
            int T = (int)ceilf(ALPHA * sigma) + 1;
            if (T > TMAX) T = TMAX;
            float v = 0.f;
            if (u >= 1 && u <= T) {
                const float tf = (float)(u - 1);
                v = __expf(-tf * tf / (2.f * sigma * sigma))
                  * __cosf(2.f * PI_F * f * tf);
            }
            ws[t] = v;
        }
    }
}

// 8192 waves: unit W = [b:2][s:5][tile:6]; each wave -> 256 outputs of the
// UNIQUE channel buffer yu[b][s][n] (no copies, no zero duty beyond its tile).
__global__ __launch_bounds__(128) void cwt_unique(
    const float* __restrict__ scales,
    const float* __restrict__ ws,
    float* __restrict__ yu)
{
    const int lane = threadIdx.x & 63;
    const int wid  = threadIdx.x >> 6;
    const int W    = blockIdx.x * 2 + wid;      // 0..8191
    const int tile = W & 63;
    const int s    = (W >> 6) & 31;
    const int b    = W >> 11;

    const int n0 = tile << 8;                   // 256-wide tiles
    float* yrow = yu + (((size_t)(b * NSCALE + s)) << 14) + n0 + lane * 4;

    const float scale = scales[s];
    const float sigma = 6.0f * scale / (2.0f * PI_F);
    int T = (int)ceilf(ALPHA * sigma) + 1;
    if (T > TMAX) T = TMAX;
    const int nG = (T + 16) >> 4;               // groups of 16 u-slots
    const int g0 = (n0 < 7937) ? ((7937 - n0) >> 4) : 0;  // tap-trim

    float a0 = 0.f, a1 = 0.f, a2 = 0.f, a3 = 0.f;

    if (g0 < nG) {
        const float4* xq = reinterpret_cast<const float4*>(
                               ws + TAPS_F + (size_t)(b * NCH + (s & 3)) * XROW)
                           + (n0 >> 2) + lane;
        const float4* tp4 = reinterpret_cast<const float4*>(ws + s * TSZ);

        float4 w0 = xq[4 * g0];
        for (int g = g0; g < nG; ++g) {
            const int j = 4 * g;
            const float4 w1 = xq[j + 1], w2 = xq[j + 2];
            const float4 w3 = xq[j + 3], w4 = xq[j + 4];
            const float4 t0 = tp4[j + 0], t1 = tp4[j + 1];
            const float4 t2 = tp4[j + 2], t3 = tp4[j + 3];

            const float e[20] = {w0.x,w0.y,w0.z,w0.w, w1.x,w1.y,w1.z,w1.w,
                                 w2.x,w2.y,w2.z,w2.w, w3.x,w3.y,w3.z,w3.w,
                                 w4.x,w4.y,w4.z,w4.w};
            const float tk[16] = {t0.x,t0.y,t0.z,t0.w, t1.x,t1.y,t1.z,t1.w,
                                  t2.x,t2.y,t2.z,t2.w, t3.x,t3.y,t3.z,t3.w};
            #pragma unroll
            for (int k = 0; k < 16; ++k) {
                a0 = fmaf(tk[k], e[k + 0], a0);
                a1 = fmaf(tk[k], e[k + 1], a1);
                a2 = fmaf(tk[k], e[k + 2], a2);
                a3 = fmaf(tk[k], e[k + 3], a3);
            }
            w0 = w4;
        }
    }

    const float4 v = {a0, a1, a2, a3};
    *reinterpret_cast<float4*>(yrow) = v;
}

// pure-BW broadcast: out[b][ch][n] = yu[b][ch%32][n], fill-shaped access.
__global__ __launch_bounds__(256) void bcast_kernel(
    const float* __restrict__ yu,
    float4* __restrict__ out4)
{
    const int i = blockIdx.x * 256 + threadIdx.x;    // 524288 threads
    const float4* yu4 = reinterpret_cast<const float4*>(yu);
    #pragma unroll
    for (int k = 0; k < 4; ++k) {
        const int o  = i + k * 524288;               // < 2097152
        const int n4 = o & 4095;
        const int ch = (o >> 12) & 127;
        const int b  = o >> 19;
        out4[o] = yu4[(((b << 5) | (ch & 31)) << 12) | n4];
    }
}

extern "C" void kernel_launch(void* const* d_in, const int* in_sizes, int n_in,
                              void* d_out, int out_size, void* d_ws, size_t ws_size,
                              hipStream_t stream) {
    const float* x      = (const float*)d_in[0];
    const float* scales = (const float*)d_in[1];
    float* out          = (float*)d_out;
    float* ws           = (float*)d_ws;     // taps 48KB + xpad 1.05MB + yu 8.4MB

    prep_kernel<<<dim3(310), 256, 0, stream>>>(x, scales, ws);
    cwt_unique<<<dim3(4096), 128, 0, stream>>>(scales, ws, ws + YU_F);
    bcast_kernel<<<dim3(2048), 256, 0, stream>>>(ws + YU_F, (float4*)out);
}

// Round 13
// 32.833 us; speedup vs baseline: 1.8707x; 1.8707x over previous
//
#include <hip/hip_runtime.h>

// CWT, truncated direct correlation, REAL PART ONLY (harness validates
// out_size = B*128*N float32 = real part of the complex64 reference).
// u-shifted: y[n] = sum_{u=1..T} xpad[n+u]*tw[u], xpad[i]=x[i-8192] (0 outside),
// tw[u] = exp(-(u-1)^2/2sig^2)*cos(2pi*f*(u-1)), sig=6*scale/2pi, f=1/scale,
// T = ceil(5*sigma)+1 <= 307 (validated absmax 0.0625 vs threshold 0.445).
// ch%4 -> x row, ch%32 -> wavelet; 4|32 -> 32 unique channels, 4 copies.
//
// R12 counters (cwt_unique 45.6us, VALU 9.5%, Occ 19.8%) exposed two causes:
// (a) power-of-2 unit decode re-created R6's CU aliasing (half the CUs got
//     only zero-region tiles);
// (b) the REAL roofline: window re-read traffic = totalFMAs*4B ~ 0.67 GB
//     through L1/L2/LDS per pass (~10-20us at near-mem BW) - shared by ALL
//     rounds 7-12, which is why every scheduling fix was null.
// R13: 4-SCALE WINDOW REUSE. Scales with equal s%4 read the same x row; one
// wave computes scales {c+4*sub+8k, k=0..3} for its (b,c,sub,tile): window
// loaded once per 16-tap group (5 float4), 256 FMAs per group (issue-bound,
// self-hiding latency), taps are wave-uniform (scalar path). Window traffic
// /4. Tile index varies mod 34 (non-pow2) -> no CU aliasing.

#define NPIX   16384
#define NSCALE 32
#define NCH    4
#define ALPHA  5.0f
#define PI_F   3.14159265358979f

#define TSZ    384                    // tap slots per scale (f4-padded, zeroed)
#define TAPS_F (NSCALE * TSZ)         // 12288 floats
#define XROW   16768                  // padded row [8192 zeros][x row][192 pad]
#define TMAX   307
#define WT0    30                     // first working 256-wide tile
#define NWT    34                     // working tiles 30..63
#define NZT    30                     // all-scale zero tiles 0..29
#define NBLOCK (NWT * 32)             // 34 tiles * (4b * 4c * 2sub) = 1088

__global__ __launch_bounds__(256) void prep_kernel(
    const float* __restrict__ x,
    const float* __restrict__ scales,
    float* __restrict__ ws)
{
    const int idx = blockIdx.x * 256 + threadIdx.x;
    if (blockIdx.x < 262) {                 // xpad: 16*16768/4 = 67072 float4
        float4* xp4 = reinterpret_cast<float4*>(ws + TAPS_F);
        const int row = idx / (XROW / 4);
        const int i   = (idx % (XROW / 4)) * 4;
        float4 v = {0.f, 0.f, 0.f, 0.f};
        if (i >= 8192 && i - 8192 < NPIX)   // aligned, no straddle
            v = *reinterpret_cast<const float4*>(x + (size_t)row * NPIX + (i - 8192));
        xp4[idx] = v;
    } else {                                 // taps: 32*384 floats, u-indexed
        const int t = idx - 262 * 256;
        if (t < TAPS_F) {
            const int s = t / TSZ, u = t % TSZ;
            const float scale = scales[s];
            const float f     = 1.0f / scale;
            const float sigma = 6.0f * scale / (2.0f * PI_F);
            int T = (int)ceilf(ALPHA * sigma) + 1;
            if (T > TMAX) T = TMAX;
            float v = 0.f;
            if (u >= 1 && u <= T) {
                const float tf = (float)(u - 1);
                v = __expf(-tf * tf / (2.f * sigma * sigma))
                  * __cosf(2.f * PI_F * f * tf);
            }
            ws[t] = v;
        }
    }
}

// 16 taps of one scale against the shared 20-float window, 4 outputs
#define FMA_SCALE(T0, T1, T2, T3, A0, A1, A2, A3)                            \
    do {                                                                     \
        const float tk[16] = {T0.x,T0.y,T0.z,T0.w, T1.x,T1.y,T1.z,T1.w,      \
                              T2.x,T2.y,T2.z,T2.w, T3.x,T3.y,T3.z,T3.w};     \
        _Pragma("unroll")                                                    \
        for (int t = 0; t < 16; ++t) {                                       \
            A0 = fmaf(tk[t], e[t + 0], A0);                                  \
            A1 = fmaf(tk[t], e[t + 1], A1);                                  \
            A2 = fmaf(tk[t], e[t + 2], A2);                                  \
            A3 = fmaf(tk[t], e[t + 3], A3);                                  \
        }                                                                    \
    } while (0)

__global__ __launch_bounds__(64) void cwt4_kernel(
    const float* __restrict__ scales,
    const float* __restrict__ ws,
    float* __restrict__ out)
{
    const int lane = threadIdx.x;
    const int Bk   = blockIdx.x;
    const int tw   = Bk % NWT;          // fastest-varying, mod 34: no aliasing
    const int rest = Bk / NWT;          // 0..31
    const int b    = rest & 3;
    const int c    = (rest >> 2) & 3;
    const int sub  = rest >> 4;         // 0..1
    const int sbase = c + 4 * sub;      // scales sbase + 8k, k=0..3 (asc)

    const size_t cstride = (size_t)NSCALE * NPIX;

    // ---- zero duty: this block zero-fills tile tw (<30) for its 4 scales ----
    if (tw < NZT) {
        const float4 z = {0.f, 0.f, 0.f, 0.f};
        #pragma unroll
        for (int k = 0; k < 4; ++k) {
            float* zp = out + ((size_t)b * (NSCALE * NCH) + (sbase + 8 * k)) * NPIX
                            + tw * 256 + lane * 4;
            #pragma unroll
            for (int q = 0; q < 4; ++q)
                *reinterpret_cast<float4*>(zp + (size_t)q * cstride) = z;
        }
    }

    // ---- per-scale trip counts (ascending in k) ----
    int nG0, nG1, nG2, nG3;
    {
        #define TRIP(K, DST)                                                 \
            do {                                                             \
                const float sc = scales[sbase + 8 * K];                      \
                const float sg = 6.0f * sc / (2.0f * PI_F);                  \
                int T = (int)ceilf(ALPHA * sg) + 1;                          \
                if (T > TMAX) T = TMAX;                                      \
                DST = (T >> 4) + 1;                                          \
            } while (0)
        TRIP(0, nG0); TRIP(1, nG1); TRIP(2, nG2); TRIP(3, nG3);
        #undef TRIP
    }
    const int nGmax = nG3;              // scales ascending -> largest T last

    const int n0 = (WT0 + tw) * 256;
    // groups with u < 8192-(n0+255) touch only zero padding for every lane
    const int umin = 8192 - n0 - 255;
    const int g0   = (umin > 0) ? (umin >> 4) : 0;

    const float4* xq = reinterpret_cast<const float4*>(
                           ws + TAPS_F + (size_t)(b * NCH + c) * XROW)
                       + (n0 >> 2) + lane;
    const float4* tpA = reinterpret_cast<const float4*>(ws + (sbase     ) * TSZ);
    const float4* tpB = reinterpret_cast<const float4*>(ws + (sbase +  8) * TSZ);
    const float4* tpC = reinterpret_cast<const float4*>(ws + (sbase + 16) * TSZ);
    const float4* tpD = reinterpret_cast<const float4*>(ws + (sbase + 24) * TSZ);

    float a00=0.f,a01=0.f,a02=0.f,a03=0.f, a10=0.f,a11=0.f,a12=0.f,a13=0.f;
    float a20=0.f,a21=0.f,a22=0.f,a23=0.f, a30=0.f,a31=0.f,a32=0.f,a33=0.f;

    if (g0 < nGmax) {
        // prologue window for group g0: floats [16*g0, 16*g0+19]
        const int j0 = 4 * g0;
        float4 w0 = xq[j0], w1 = xq[j0+1], w2 = xq[j0+2],
               w3 = xq[j0+3], w4 = xq[j0+4];

        for (int g = g0; g < nGmax; ++g) {
            const int j = 4 * g;
            // issue next-group window loads early (independent of FMAs below)
            const float4 x1 = xq[j+5], x2 = xq[j+6], x3 = xq[j+7], x4 = xq[j+8];

            const float e[20] = {w0.x,w0.y,w0.z,w0.w, w1.x,w1.y,w1.z,w1.w,
                                 w2.x,w2.y,w2.z,w2.w, w3.x,w3.y,w3.z,w3.w,
                                 w4.x,w4.y,w4.z,w4.w};

            if (g < nG0) {
                const float4 t0 = tpA[j], t1 = tpA[j+1], t2 = tpA[j+2], t3 = tpA[j+3];
                FMA_SCALE(t0, t1, t2, t3, a00, a01, a02, a03);
            }
            if (g < nG1) {
                const float4 t0 = tpB[j], t1 = tpB[j+1], t2 = tpB[j+2], t3 = tpB[j+3];
                FMA_SCALE(t0, t1, t2, t3, a10, a11, a12, a13);
            }
            if (g < nG2) {
                const float4 t0 = tpC[j], t1 = tpC[j+1], t2 = tpC[j+2], t3 = tpC[j+3];
                FMA_SCALE(t0, t1, t2, t3, a20, a21, a22, a23);
            }
            {
                const float4 t0 = tpD[j], t1 = tpD[j+1], t2 = tpD[j+2], t3 = tpD[j+3];
                FMA_SCALE(t0, t1, t2, t3, a30, a31, a32, a33);
            }

            w0 = x1.x == x1.x ? w4 : w4;   // keep simple: rotate
            w0 = w4; w1 = x1; w2 = x2; w3 = x3; w4 = x4;
        }
    }

    // ---- store: 4 scales x 4 channel copies, coalesced float4 ----
    float* ob = out + ((size_t)b * (NSCALE * NCH)) * NPIX + n0 + lane * 4;
    #pragma unroll
    for (int k = 0; k < 4; ++k) {
        float4 v;
        if (k == 0) v = make_float4(a00, a01, a02, a03);
        if (k == 1) v = make_float4(a10, a11, a12, a13);
        if (k == 2) v = make_float4(a20, a21, a22, a23);
        if (k == 3) v = make_float4(a30, a31, a32, a33);
        float* os = ob + (size_t)(sbase + 8 * k) * NPIX;
        #pragma unroll
        for (int q = 0; q < 4; ++q)
            *reinterpret_cast<float4*>(os + (size_t)q * cstride) = v;
    }
}

extern "C" void kernel_launch(void* const* d_in, const int* in_sizes, int n_in,
                              void* d_out, int out_size, void* d_ws, size_t ws_size,
                              hipStream_t stream) {
    const float* x      = (const float*)d_in[0];
    const float* scales = (const float*)d_in[1];
    float* out          = (float*)d_out;
    float* ws           = (float*)d_ws;   // taps 48KB + xpad 1.05MB

    prep_kernel<<<dim3(310), 256, 0, stream>>>(x, scales, ws);
    cwt4_kernel<<<dim3(NBLOCK), 64, 0, stream>>>(scales, ws, out);
}

// Round 14
// 23.966 us; speedup vs baseline: 2.5628x; 1.3700x over previous
//
#include <hip/hip_runtime.h>

// CWT, truncated direct correlation, REAL PART ONLY (harness validates
// out_size = B*128*N float32 = real part of the complex64 reference).
//   y[n] = sum_{u=1..T} xpad[n+u]*tw[u], xpad[i]=x[i-8192] (0 outside),
//   tw[u] = exp(-(u-1)^2/2sig^2)*cos(2pi*(u-1)/scale), sig = 6*scale/2pi,
//   T = ceil(5*sigma)+1 <= 307  (validated absmax 0.0625 vs threshold 0.445).
// ch%4 -> x row, ch%32 -> wavelet; 4|32 -> 32 unique channels, 4 copies.
// Tiles 0..29 (256-wide) are exactly zero for all scales.
//
// R14 (consolidation): SINGLE dispatch. Per block (1 wave): compute taps for
// its 4 scales {c+4sub+8k} into LDS (~20 exp/cos per lane, once), stage the
// x window into LDS (3 float4 loads/lane), then 16-tap groups with 4-scale
// window reuse; tap reads are LDS broadcasts interleaved between FMA bursts.
// Block map: tile = 30 + (r34 + q) % 34 -> every CU samples spread tiles,
// no pow-2 aliasing. Zero tiles written by blocks with r34 < 30.

#define NPIX   16384
#define NSCALE 32
#define ALPHA  5.0f
#define PI_F   3.14159265358979f
#define TPS4   80        // tap float4s per scale (320 floats, zero-padded)
#define SPAN4  152       // staged window float4s (608 floats)
#define WT0    30
#define NWT    34
#define NZT    30
#define NBLOCK (NWT * 32)   // 1088

#define FMA_SCALE(T0, T1, T2, T3, A0, A1, A2, A3)                            \
    do {                                                                     \
        const float tk[16] = {T0.x,T0.y,T0.z,T0.w, T1.x,T1.y,T1.z,T1.w,      \
                              T2.x,T2.y,T2.z,T2.w, T3.x,T3.y,T3.z,T3.w};     \
        _Pragma("unroll")                                                    \
        for (int t = 0; t < 16; ++t) {                                       \
            A0 = fmaf(tk[t], e[t + 0], A0);                                  \
            A1 = fmaf(tk[t], e[t + 1], A1);                                  \
            A2 = fmaf(tk[t], e[t + 2], A2);                                  \
            A3 = fmaf(tk[t], e[t + 3], A3);                                  \
        }                                                                    \
    } while (0)

__global__ __launch_bounds__(64) void cwt_kernel(
    const float* __restrict__ x,
    const float* __restrict__ scales,
    float* __restrict__ out)
{
    __shared__ float4 tl4[4][TPS4];   // 4 scales x 320 taps  = 5 KB
    __shared__ float4 xs4[SPAN4];     // 608-float x window   = 2.4 KB

    const int lane = threadIdx.x;
    const int Bk   = blockIdx.x;
    const int q    = Bk / NWT;               // 0..31 = (b,c,sub)
    const int r34  = Bk - q * NWT;           // 0..33
    const int b    = q >> 3;
    const int c    = (q >> 1) & 3;
    const int sub  = q & 1;
    int twr = r34 + q; if (twr >= NWT) twr -= NWT;   // rotation, bijective per q
    const int n0   = (WT0 + twr) << 8;
    const int sb   = c + (sub << 2);         // scales sb + 8k, k=0..3 (ascending)

    const size_t cstride = (size_t)NSCALE * NPIX;

    // ---- zero duty: block's r34 (<30) names the zero tile it fills ----
    if (r34 < NZT) {
        const float4 z = {0.f, 0.f, 0.f, 0.f};
        #pragma unroll
        for (int k = 0; k < 4; ++k) {
            float* zp = out + ((size_t)b * 128 + (sb + 8 * k)) * NPIX
                            + (r34 << 8) + (lane << 2);
            #pragma unroll
            for (int q4 = 0; q4 < 4; ++q4)
                *reinterpret_cast<float4*>(zp + (size_t)q4 * cstride) = z;
        }
    }

    // ---- per-scale params (static names, rule #20) ----
    const float sc0 = scales[sb],      sc1 = scales[sb + 8];
    const float sc2 = scales[sb + 16], sc3 = scales[sb + 24];
#define PARAMS(SC, SG, TT, W2, C2)                                            \
    const float SG = 6.0f * SC / (2.0f * PI_F);                               \
    int TT = (int)ceilf(ALPHA * SG) + 1; if (TT > 307) TT = 307;              \
    const float W2 = 2.0f * PI_F / SC;                                        \
    const float C2 = -0.5f / (SG * SG);
    PARAMS(sc0, sg0, T0, w2_0, c2_0)
    PARAMS(sc1, sg1, T1, w2_1, c2_1)
    PARAMS(sc2, sg2, T2, w2_2, c2_2)
    PARAMS(sc3, sg3, T3, w2_3, c2_3)
#undef PARAMS

    // ---- taps into LDS: u-indexed, tl[k][u] = tw_k[u], zero-padded ----
    {
        float* tl0 = reinterpret_cast<float*>(tl4[0]);
        float* tl1 = reinterpret_cast<float*>(tl4[1]);
        float* tl2 = reinterpret_cast<float*>(tl4[2]);
        float* tl3 = reinterpret_cast<float*>(tl4[3]);
        #pragma unroll
        for (int m = 0; m < 5; ++m) {
            const int u = lane + (m << 6);          // 0..319
            const float tf = (float)(u - 1);
            const float t2 = tf * tf;
#define TAP(DST, TT, C2, W2)                                                  \
            DST[u] = (u >= 1 && u <= TT)                                      \
                   ? __expf(C2 * t2) * __cosf(W2 * tf) : 0.0f;
            TAP(tl0, T0, c2_0, w2_0)
            TAP(tl1, T1, c2_1, w2_1)
            TAP(tl2, T2, c2_2, w2_2)
            TAP(tl3, T3, c2_3, w2_3)
#undef TAP
        }
    }

    // ---- stage x window: xs[i] = xpad[n0 + i] = x[n0 + i - 8192] ----
    {
        const float* xrow = x + (size_t)(b * 4 + c) * NPIX;
        #pragma unroll
        for (int m = 0; m < 3; ++m) {
            const int i4 = lane + (m << 6);
            if (i4 < SPAN4) {
                const int gi = n0 - 8192 + (i4 << 2);
                float4 v = {0.f, 0.f, 0.f, 0.f};
                if (gi >= 0)
                    v = *reinterpret_cast<const float4*>(xrow + gi);
                xs4[i4] = v;
            }
        }
    }
    // single wave: in-wave LDS write->read ordering via compiler lgkmcnt.

    const int nG0 = (T0 >> 4) + 1, nG1 = (T1 >> 4) + 1;
    const int nG2 = (T2 >> 4) + 1, nGmax = (T3 >> 4) + 1;   // ascending T
    const int umin = 8192 - n0 - 255;
    const int g0   = (umin > 0) ? (umin >> 4) : 0;

    float a00=0.f,a01=0.f,a02=0.f,a03=0.f, a10=0.f,a11=0.f,a12=0.f,a13=0.f;
    float a20=0.f,a21=0.f,a22=0.f,a23=0.f, a30=0.f,a31=0.f,a32=0.f,a33=0.f;

    if (g0 < nGmax) {
        const int jw = lane + (g0 << 2);
        float4 w0 = xs4[jw],   w1 = xs4[jw+1], w2 = xs4[jw+2],
               w3 = xs4[jw+3], w4 = xs4[jw+4];

        for (int g = g0; g < nGmax; ++g) {
            const int jt = g << 2;
            const int jx = lane + jt;

            // scale-A taps first; later scales' loads interleave with FMAs
            const float4 tA0 = tl4[0][jt], tA1 = tl4[0][jt+1],
                         tA2 = tl4[0][jt+2], tA3 = tl4[0][jt+3];
            const float e[20] = {w0.x,w0.y,w0.z,w0.w, w1.x,w1.y,w1.z,w1.w,
                                 w2.x,w2.y,w2.z,w2.w, w3.x,w3.y,w3.z,w3.w,
                                 w4.x,w4.y,w4.z,w4.w};
            const float4 tB0 = tl4[1][jt], tB1 = tl4[1][jt+1],
                         tB2 = tl4[1][jt+2], tB3 = tl4[1][jt+3];
            if (g < nG0) FMA_SCALE(tA0, tA1, tA2, tA3, a00, a01, a02, a03);
            const float4 tC0 = tl4[2][jt], tC1 = tl4[2][jt+1],
                         tC2 = tl4[2][jt+2], tC3 = tl4[2][jt+3];
            if (g < nG1) FMA_SCALE(tB0, tB1, tB2, tB3, a10, a11, a12, a13);
            const float4 tD0 = tl4[3][jt], tD1 = tl4[3][jt+1],
                         tD2 = tl4[3][jt+2], tD3 = tl4[3][jt+3];
            if (g < nG2) FMA_SCALE(tC0, tC1, tC2, tC3, a20, a21, a22, a23);
            // next-group window loads issued before the last FMA burst
            const float4 x1 = xs4[jx+5], x2 = xs4[jx+6],
                         x3 = xs4[jx+7], x4 = xs4[jx+8];
            FMA_SCALE(tD0, tD1, tD2, tD3, a30, a31, a32, a33);

            w0 = w4; w1 = x1; w2 = x2; w3 = x3; w4 = x4;
        }
    }

    // ---- store: 4 scales x 4 channel copies ----
    float* ob = out + (size_t)b * 128 * NPIX + n0 + (lane << 2);
    #pragma unroll
    for (int k = 0; k < 4; ++k) {
        float4 v;
        if (k == 0) v = make_float4(a00, a01, a02, a03);
        if (k == 1) v = make_float4(a10, a11, a12, a13);
        if (k == 2) v = make_float4(a20, a21, a22, a23);
        if (k == 3) v = make_float4(a30, a31, a32, a33);
        float* os = ob + (size_t)(sb + 8 * k) * NPIX;
        #pragma unroll
        for (int q4 = 0; q4 < 4; ++q4)
            *reinterpret_cast<float4*>(os + (size_t)q4 * cstride) = v;
    }
}

extern "C" void kernel_launch(void* const* d_in, const int* in_sizes, int n_in,
                              void* d_out, int out_size, void* d_ws, size_t ws_size,
                              hipStream_t stream) {
    const float* x      = (const float*)d_in[0];
    const float* scales = (const float*)d_in[1];
    float* out          = (float*)d_out;

    cwt_kernel<<<dim3(NBLOCK), 64, 0, stream>>>(x, scales, out);
}